// Round 1
// baseline (727.278 us; speedup 1.0000x reference)
//
#include <hip/hip_runtime.h>
#include <math.h>

#define TOK 25
#define KC 512

// ---------------- patchify: x[1,256,20,20] -> P[25][4096] (idx = c*16+kh*4+kw)
__global__ __launch_bounds__(256) void k_patchify(const float* __restrict__ x,
                                                  float* __restrict__ P) {
  int idx = blockIdx.x * 256 + threadIdx.x;  // 0..102399
  int n = idx >> 12;
  int rem = idx & 4095;
  int c = rem >> 4;
  int kh = (rem >> 2) & 3;
  int kw = rem & 3;
  int py = n / 5, px = n - py * 5;
  P[idx] = x[c * 400 + (py * 4 + kh) * 20 + (px * 4 + kw)];
}

// ---------------- GEMM, W in [Nout][K] layout (conv weight). partial[S][25][Nout]
__global__ __launch_bounds__(256) void k_gemm_wt(const float* __restrict__ A,
                                                 const float* __restrict__ W,
                                                 float* __restrict__ part,
                                                 int K, int Nout) {
  __shared__ float As[TOK * KC];
  const int s = blockIdx.y;
  const int k0 = s * KC;
  const int o = blockIdx.x * 256 + threadIdx.x;
  for (int i = threadIdx.x; i < TOK * (KC / 4); i += 256) {
    int r = i / (KC / 4);
    int k4 = i - r * (KC / 4);
    reinterpret_cast<float4*>(As)[i] =
        reinterpret_cast<const float4*>(A + (long)r * K + k0)[k4];
  }
  __syncthreads();
  float acc[TOK];
#pragma unroll
  for (int r = 0; r < TOK; ++r) acc[r] = 0.f;
  const float* wp = W + (long)o * K + k0;
  for (int kk = 0; kk < KC; kk += 4) {
    float4 w4 = *reinterpret_cast<const float4*>(wp + kk);
#pragma unroll
    for (int r = 0; r < TOK; ++r) {
      float4 a = *reinterpret_cast<const float4*>(&As[r * KC + kk]);
      acc[r] = fmaf(a.x, w4.x, acc[r]);
      acc[r] = fmaf(a.y, w4.y, acc[r]);
      acc[r] = fmaf(a.z, w4.z, acc[r]);
      acc[r] = fmaf(a.w, w4.w, acc[r]);
    }
  }
  float* pp = part + ((long)s * TOK) * Nout + o;
#pragma unroll
  for (int r = 0; r < TOK; ++r) pp[(long)r * Nout] = acc[r];
}

// ---------------- GEMM, W in [K][Nout] layout (all linear layers)
__global__ __launch_bounds__(256) void k_gemm(const float* __restrict__ A,
                                              const float* __restrict__ W,
                                              float* __restrict__ part,
                                              int K, int Nout) {
  __shared__ float As[TOK * KC];
  const int s = blockIdx.y;
  const int k0 = s * KC;
  const int c = blockIdx.x * 256 + threadIdx.x;
  for (int i = threadIdx.x; i < TOK * (KC / 4); i += 256) {
    int r = i / (KC / 4);
    int k4 = i - r * (KC / 4);
    reinterpret_cast<float4*>(As)[i] =
        reinterpret_cast<const float4*>(A + (long)r * K + k0)[k4];
  }
  __syncthreads();
  float acc[TOK];
#pragma unroll
  for (int r = 0; r < TOK; ++r) acc[r] = 0.f;
  const long ldw = Nout;
  const float* wp = W + (long)k0 * ldw + c;
  for (int kk = 0; kk < KC; kk += 4) {
    float w0 = wp[0];
    float w1 = wp[ldw];
    float w2 = wp[2 * ldw];
    float w3 = wp[3 * ldw];
    wp += 4 * ldw;
#pragma unroll
    for (int r = 0; r < TOK; ++r) {
      float4 a = *reinterpret_cast<const float4*>(&As[r * KC + kk]);
      acc[r] = fmaf(a.x, w0, acc[r]);
      acc[r] = fmaf(a.y, w1, acc[r]);
      acc[r] = fmaf(a.z, w2, acc[r]);
      acc[r] = fmaf(a.w, w3, acc[r]);
    }
  }
  float* pp = part + ((long)s * TOK) * Nout + c;
#pragma unroll
  for (int r = 0; r < TOK; ++r) pp[(long)r * Nout] = acc[r];
}

// ---------------- reduce partials + bias (+gelu) (+residual). grid covers 25*Nout exactly
template <int GELU, int RES>
__global__ __launch_bounds__(256) void k_reduce(const float* __restrict__ part,
                                                const float* __restrict__ bias,
                                                const float* __restrict__ res,
                                                float* __restrict__ out,
                                                int Nout, int S) {
  long idx = (long)blockIdx.x * 256 + threadIdx.x;
  int c = (int)(idx % Nout);
  const long stride = (long)TOK * Nout;
  float v = 0.f;
  for (int s = 0; s < S; ++s) v += part[s * stride + idx];
  v += bias[c];
  if (GELU) v = 0.5f * v * (1.f + erff(v * 0.70710678118654752f));
  if (RES) v += res[idx];
  out[idx] = v;
}

// ---------------- LayerNorm over 4096, one block per token
__global__ __launch_bounds__(256) void k_ln(const float* __restrict__ t,
                                            const float* __restrict__ g,
                                            const float* __restrict__ b,
                                            float* __restrict__ h) {
  const int n = blockIdx.x;
  const float4* row = reinterpret_cast<const float4*>(t + n * 4096);
  float s = 0.f, s2 = 0.f;
  float4 vbuf[4];
#pragma unroll
  for (int it = 0; it < 4; ++it) {
    float4 v = row[threadIdx.x + it * 256];
    vbuf[it] = v;
    s += v.x + v.y + v.z + v.w;
    s2 += v.x * v.x + v.y * v.y + v.z * v.z + v.w * v.w;
  }
#pragma unroll
  for (int off = 32; off >= 1; off >>= 1) {
    s += __shfl_down(s, off);
    s2 += __shfl_down(s2, off);
  }
  __shared__ float red[8];
  if ((threadIdx.x & 63) == 0) {
    red[threadIdx.x >> 6] = s;
    red[4 + (threadIdx.x >> 6)] = s2;
  }
  __syncthreads();
  float st = red[0] + red[1] + red[2] + red[3];
  float s2t = red[4] + red[5] + red[6] + red[7];
  float mean = st * (1.f / 4096.f);
  float var = s2t * (1.f / 4096.f) - mean * mean;
  float rstd = rsqrtf(var + 1e-5f);
  const float4* g4 = reinterpret_cast<const float4*>(g);
  const float4* b4 = reinterpret_cast<const float4*>(b);
  float4* h4 = reinterpret_cast<float4*>(h + n * 4096);
#pragma unroll
  for (int it = 0; it < 4; ++it) {
    int i = threadIdx.x + it * 256;
    float4 v = vbuf[it];
    float4 gg = g4[i];
    float4 bb = b4[i];
    float4 o;
    o.x = (v.x - mean) * rstd * gg.x + bb.x;
    o.y = (v.y - mean) * rstd * gg.y + bb.y;
    o.z = (v.z - mean) * rstd * gg.z + bb.z;
    o.w = (v.w - mean) * rstd * gg.w + bb.w;
    h4[i] = o;
  }
}

// ---------------- attention: QK^T + softmax/64 -> att[16][25][25]
__global__ __launch_bounds__(256) void k_attn_qk(const float* __restrict__ qkv,
                                                 float* __restrict__ att) {
  const int head = blockIdx.x;
  __shared__ float q[TOK][260];
  __shared__ float k[TOK][260];
  __shared__ float e[TOK][TOK];
  const int d = threadIdx.x;
#pragma unroll
  for (int n = 0; n < TOK; ++n) {
    const long base = (long)n * 12288 + (head * 256 + d) * 3;
    q[n][d] = qkv[base];
    k[n][d] = qkv[base + 1];
  }
  __syncthreads();
  for (int p = threadIdx.x; p < TOK * TOK; p += 256) {
    int i = p / TOK, j = p - i * TOK;
    float acc = 0.f;
#pragma unroll
    for (int kk = 0; kk < 256; kk += 4) {
      float4 a = *reinterpret_cast<const float4*>(&q[i][kk]);
      float4 bb = *reinterpret_cast<const float4*>(&k[j][kk]);
      acc = fmaf(a.x, bb.x, acc);
      acc = fmaf(a.y, bb.y, acc);
      acc = fmaf(a.z, bb.z, acc);
      acc = fmaf(a.w, bb.w, acc);
    }
    e[i][j] = acc;
  }
  __syncthreads();
  if (threadIdx.x < TOK) {
    const int i = threadIdx.x;
    float m = -1e30f;
    for (int j = 0; j < TOK; ++j) m = fmaxf(m, e[i][j]);
    float ssum = 0.f;
    float ex[TOK];
#pragma unroll
    for (int j = 0; j < TOK; ++j) {
      ex[j] = expf(e[i][j] - m);
      ssum += ex[j];
    }
    float inv = 1.f / (ssum * 64.f);  // softmax then /sqrt(4096)
#pragma unroll
    for (int j = 0; j < TOK; ++j) att[head * 625 + i * TOK + j] = ex[j] * inv;
  }
}

// ---------------- attention: att @ V -> o[25][4096]
__global__ __launch_bounds__(256) void k_attn_pv(const float* __restrict__ qkv,
                                                 const float* __restrict__ att,
                                                 float* __restrict__ o) {
  const int head = blockIdx.x;
  const int d = threadIdx.x;
  __shared__ float a[TOK * TOK];
  for (int i = threadIdx.x; i < TOK * TOK; i += 256) a[i] = att[head * 625 + i];
  __syncthreads();
  float acc[TOK];
#pragma unroll
  for (int i = 0; i < TOK; ++i) acc[i] = 0.f;
  for (int j = 0; j < TOK; ++j) {
    float vv = qkv[(long)j * 12288 + (head * 256 + d) * 3 + 2];
#pragma unroll
    for (int i = 0; i < TOK; ++i) acc[i] = fmaf(a[i * TOK + j], vv, acc[i]);
  }
#pragma unroll
  for (int i = 0; i < TOK; ++i) o[(long)i * 4096 + head * 256 + d] = acc[i];
}

extern "C" void kernel_launch(void* const* d_in, const int* in_sizes, int n_in,
                              void* d_out, int out_size, void* d_ws, size_t ws_size,
                              hipStream_t stream) {
  (void)in_sizes; (void)n_in; (void)out_size; (void)ws_size;
  const float* x      = (const float*)d_in[0];
  const float* pe_w   = (const float*)d_in[1];
  const float* pe_b   = (const float*)d_in[2];
  const float* pos    = (const float*)d_in[3];
  const float* ln_g   = (const float*)d_in[4];
  const float* ln_b   = (const float*)d_in[5];
  const float* qkv_w  = (const float*)d_in[6];
  const float* qkv_b  = (const float*)d_in[7];
  const float* proj_w = (const float*)d_in[8];
  const float* proj_b = (const float*)d_in[9];
  const float* ff1_w  = (const float*)d_in[10];
  const float* ff1_b  = (const float*)d_in[11];
  const float* ff2_w  = (const float*)d_in[12];
  const float* ff2_b  = (const float*)d_in[13];
  float* out = (float*)d_out;

  float* ws = (float*)d_ws;
  float* P    = ws;             // 102400
  float* T    = ws + 102400;    // 102400
  float* H    = ws + 204800;    // 102400
  float* QKV  = ws + 307200;    // 307200
  float* O    = ws + 614400;    // 102400
  float* G    = ws + 716800;    // 409600
  float* ATT  = ws + 1126400;   // 10000
  float* PART = ws + 1136400;   // up to 3276800

  // 1. patch embedding
  k_patchify<<<400, 256, 0, stream>>>(x, P);
  k_gemm_wt<<<dim3(16, 8), 256, 0, stream>>>(P, pe_w, PART, 4096, 4096);
  k_reduce<0, 1><<<400, 256, 0, stream>>>(PART, pe_b, pos, T, 4096, 8);

  // 2. attention branch
  k_ln<<<25, 256, 0, stream>>>(T, ln_g, ln_b, H);
  k_gemm<<<dim3(48, 8), 256, 0, stream>>>(H, qkv_w, PART, 4096, 12288);
  k_reduce<0, 0><<<1200, 256, 0, stream>>>(PART, qkv_b, nullptr, QKV, 12288, 8);
  k_attn_qk<<<16, 256, 0, stream>>>(QKV, ATT);
  k_attn_pv<<<16, 256, 0, stream>>>(QKV, ATT, O);
  k_gemm<<<dim3(16, 8), 256, 0, stream>>>(O, proj_w, PART, 4096, 4096);
  k_reduce<0, 1><<<400, 256, 0, stream>>>(PART, proj_b, T, T, 4096, 8);

  // 3. FFN branch
  k_ln<<<25, 256, 0, stream>>>(T, ln_g, ln_b, H);
  k_gemm<<<dim3(64, 8), 256, 0, stream>>>(H, ff1_w, PART, 4096, 16384);
  k_reduce<1, 0><<<1600, 256, 0, stream>>>(PART, ff1_b, nullptr, G, 16384, 8);
  k_gemm<<<dim3(16, 32), 256, 0, stream>>>(G, ff2_w, PART, 16384, 4096);
  k_reduce<0, 1><<<400, 256, 0, stream>>>(PART, ff2_b, T, out, 4096, 32);
}

// Round 2
// 411.327 us; speedup vs baseline: 1.7681x; 1.7681x over previous
//
#include <hip/hip_runtime.h>
#include <math.h>

#define TOK 25

// ---------------- patchify: x[1,256,20,20] -> P[25][4096] (idx = c*16+kh*4+kw)
__global__ __launch_bounds__(256) void k_patchify(const float* __restrict__ x,
                                                  float* __restrict__ P) {
  int idx = blockIdx.x * 256 + threadIdx.x;  // 0..102399
  int n = idx >> 12;
  int rem = idx & 4095;
  int c = rem >> 4;
  int kh = (rem >> 2) & 3;
  int kw = rem & 3;
  int py = n / 5, px = n - py * 5;
  P[idx] = x[c * 400 + (py * 4 + kh) * 20 + (px * 4 + kw)];
}

// ---------------- GEMM, W in [Nout][K] layout (conv weight). partial[S][25][Nout]
template <int KCV>
__global__ __launch_bounds__(256) void k_gemm_wt(const float* __restrict__ A,
                                                 const float* __restrict__ W,
                                                 float* __restrict__ part,
                                                 int K, int Nout) {
  __shared__ float As[TOK * KCV];
  const int s = blockIdx.y;
  const int k0 = s * KCV;
  const int o = blockIdx.x * 256 + threadIdx.x;
  for (int i = threadIdx.x; i < TOK * (KCV / 4); i += 256) {
    int r = i / (KCV / 4);
    int k4 = i - r * (KCV / 4);
    reinterpret_cast<float4*>(As)[i] =
        reinterpret_cast<const float4*>(A + (long)r * K + k0)[k4];
  }
  __syncthreads();
  float acc[TOK];
#pragma unroll
  for (int r = 0; r < TOK; ++r) acc[r] = 0.f;
  const float* wp = W + (long)o * K + k0;
  for (int kk = 0; kk < KCV; kk += 8) {
    float4 wa = *reinterpret_cast<const float4*>(wp + kk);
    float4 wb = *reinterpret_cast<const float4*>(wp + kk + 4);
#pragma unroll
    for (int r = 0; r < TOK; ++r) {
      float4 a = *reinterpret_cast<const float4*>(&As[r * KCV + kk]);
      float4 a2 = *reinterpret_cast<const float4*>(&As[r * KCV + kk + 4]);
      acc[r] = fmaf(a.x, wa.x, acc[r]);
      acc[r] = fmaf(a.y, wa.y, acc[r]);
      acc[r] = fmaf(a.z, wa.z, acc[r]);
      acc[r] = fmaf(a.w, wa.w, acc[r]);
      acc[r] = fmaf(a2.x, wb.x, acc[r]);
      acc[r] = fmaf(a2.y, wb.y, acc[r]);
      acc[r] = fmaf(a2.z, wb.z, acc[r]);
      acc[r] = fmaf(a2.w, wb.w, acc[r]);
    }
  }
  float* pp = part + ((long)s * TOK) * Nout + o;
#pragma unroll
  for (int r = 0; r < TOK; ++r) pp[(long)r * Nout] = acc[r];
}

// ---------------- GEMM, W in [K][Nout] layout (all linear layers)
template <int KCV>
__global__ __launch_bounds__(256) void k_gemm(const float* __restrict__ A,
                                              const float* __restrict__ W,
                                              float* __restrict__ part,
                                              int K, int Nout) {
  __shared__ float As[TOK * KCV];
  const int s = blockIdx.y;
  const int k0 = s * KCV;
  const int c = blockIdx.x * 256 + threadIdx.x;
  for (int i = threadIdx.x; i < TOK * (KCV / 4); i += 256) {
    int r = i / (KCV / 4);
    int k4 = i - r * (KCV / 4);
    reinterpret_cast<float4*>(As)[i] =
        reinterpret_cast<const float4*>(A + (long)r * K + k0)[k4];
  }
  __syncthreads();
  float acc[TOK];
#pragma unroll
  for (int r = 0; r < TOK; ++r) acc[r] = 0.f;
  const long ldw = Nout;
  const float* wp = W + (long)k0 * ldw + c;
  for (int kk = 0; kk < KCV; kk += 8) {
    float w0 = wp[0];
    float w1 = wp[ldw];
    float w2 = wp[2 * ldw];
    float w3 = wp[3 * ldw];
    float w4 = wp[4 * ldw];
    float w5 = wp[5 * ldw];
    float w6 = wp[6 * ldw];
    float w7 = wp[7 * ldw];
    wp += 8 * ldw;
#pragma unroll
    for (int r = 0; r < TOK; ++r) {
      float4 a = *reinterpret_cast<const float4*>(&As[r * KCV + kk]);
      float4 a2 = *reinterpret_cast<const float4*>(&As[r * KCV + kk + 4]);
      acc[r] = fmaf(a.x, w0, acc[r]);
      acc[r] = fmaf(a.y, w1, acc[r]);
      acc[r] = fmaf(a.z, w2, acc[r]);
      acc[r] = fmaf(a.w, w3, acc[r]);
      acc[r] = fmaf(a2.x, w4, acc[r]);
      acc[r] = fmaf(a2.y, w5, acc[r]);
      acc[r] = fmaf(a2.z, w6, acc[r]);
      acc[r] = fmaf(a2.w, w7, acc[r]);
    }
  }
  float* pp = part + ((long)s * TOK) * Nout + c;
#pragma unroll
  for (int r = 0; r < TOK; ++r) pp[(long)r * Nout] = acc[r];
}

// ---------------- reduce partials + bias (+gelu) (+residual), float4 per thread
template <int GELU, int RES>
__global__ __launch_bounds__(256) void k_reduce(const float* __restrict__ part,
                                                const float* __restrict__ bias,
                                                const float* __restrict__ res,
                                                float* __restrict__ out,
                                                int Nout, int S) {
  long idx4 = (long)blockIdx.x * 256 + threadIdx.x;  // float4 index
  int c4 = (int)(idx4 % (Nout >> 2));
  const long stride4 = (long)TOK * (Nout >> 2);
  const float4* p4 = reinterpret_cast<const float4*>(part) + idx4;
  float4 v = {0.f, 0.f, 0.f, 0.f};
  for (int s = 0; s < S; ++s) {
    float4 t = p4[s * stride4];
    v.x += t.x; v.y += t.y; v.z += t.z; v.w += t.w;
  }
  float4 bb = reinterpret_cast<const float4*>(bias)[c4];
  v.x += bb.x; v.y += bb.y; v.z += bb.z; v.w += bb.w;
  if (GELU) {
    v.x = 0.5f * v.x * (1.f + erff(v.x * 0.70710678118654752f));
    v.y = 0.5f * v.y * (1.f + erff(v.y * 0.70710678118654752f));
    v.z = 0.5f * v.z * (1.f + erff(v.z * 0.70710678118654752f));
    v.w = 0.5f * v.w * (1.f + erff(v.w * 0.70710678118654752f));
  }
  if (RES) {
    float4 rr = reinterpret_cast<const float4*>(res)[idx4];
    v.x += rr.x; v.y += rr.y; v.z += rr.z; v.w += rr.w;
  }
  reinterpret_cast<float4*>(out)[idx4] = v;
}

// ---------------- LayerNorm over 4096, one block per token
__global__ __launch_bounds__(256) void k_ln(const float* __restrict__ t,
                                            const float* __restrict__ g,
                                            const float* __restrict__ b,
                                            float* __restrict__ h) {
  const int n = blockIdx.x;
  const float4* row = reinterpret_cast<const float4*>(t + n * 4096);
  float s = 0.f, s2 = 0.f;
  float4 vbuf[4];
#pragma unroll
  for (int it = 0; it < 4; ++it) {
    float4 v = row[threadIdx.x + it * 256];
    vbuf[it] = v;
    s += v.x + v.y + v.z + v.w;
    s2 += v.x * v.x + v.y * v.y + v.z * v.z + v.w * v.w;
  }
#pragma unroll
  for (int off = 32; off >= 1; off >>= 1) {
    s += __shfl_down(s, off);
    s2 += __shfl_down(s2, off);
  }
  __shared__ float red[8];
  if ((threadIdx.x & 63) == 0) {
    red[threadIdx.x >> 6] = s;
    red[4 + (threadIdx.x >> 6)] = s2;
  }
  __syncthreads();
  float st = red[0] + red[1] + red[2] + red[3];
  float s2t = red[4] + red[5] + red[6] + red[7];
  float mean = st * (1.f / 4096.f);
  float var = s2t * (1.f / 4096.f) - mean * mean;
  float rstd = rsqrtf(var + 1e-5f);
  const float4* g4 = reinterpret_cast<const float4*>(g);
  const float4* b4 = reinterpret_cast<const float4*>(b);
  float4* h4 = reinterpret_cast<float4*>(h + n * 4096);
#pragma unroll
  for (int it = 0; it < 4; ++it) {
    int i = threadIdx.x + it * 256;
    float4 v = vbuf[it];
    float4 gg = g4[i];
    float4 bb = b4[i];
    float4 o;
    o.x = (v.x - mean) * rstd * gg.x + bb.x;
    o.y = (v.y - mean) * rstd * gg.y + bb.y;
    o.z = (v.z - mean) * rstd * gg.z + bb.z;
    o.w = (v.w - mean) * rstd * gg.w + bb.w;
    h4[i] = o;
  }
}

// ---------------- attention: QK^T + softmax/64 -> att[16][25][25]
__global__ __launch_bounds__(256) void k_attn_qk(const float* __restrict__ qkv,
                                                 float* __restrict__ att) {
  const int head = blockIdx.x;
  __shared__ float q[TOK][260];
  __shared__ float k[TOK][260];
  __shared__ float e[TOK][TOK];
  const int d = threadIdx.x;
#pragma unroll
  for (int n = 0; n < TOK; ++n) {
    const long base = (long)n * 12288 + (head * 256 + d) * 3;
    q[n][d] = qkv[base];
    k[n][d] = qkv[base + 1];
  }
  __syncthreads();
  for (int p = threadIdx.x; p < TOK * TOK; p += 256) {
    int i = p / TOK, j = p - i * TOK;
    float acc = 0.f;
#pragma unroll
    for (int kk = 0; kk < 256; kk += 4) {
      float4 a = *reinterpret_cast<const float4*>(&q[i][kk]);
      float4 bb = *reinterpret_cast<const float4*>(&k[j][kk]);
      acc = fmaf(a.x, bb.x, acc);
      acc = fmaf(a.y, bb.y, acc);
      acc = fmaf(a.z, bb.z, acc);
      acc = fmaf(a.w, bb.w, acc);
    }
    e[i][j] = acc;
  }
  __syncthreads();
  if (threadIdx.x < TOK) {
    const int i = threadIdx.x;
    float m = -1e30f;
    for (int j = 0; j < TOK; ++j) m = fmaxf(m, e[i][j]);
    float ssum = 0.f;
    float ex[TOK];
#pragma unroll
    for (int j = 0; j < TOK; ++j) {
      ex[j] = expf(e[i][j] - m);
      ssum += ex[j];
    }
    float inv = 1.f / (ssum * 64.f);  // softmax then /sqrt(4096)
#pragma unroll
    for (int j = 0; j < TOK; ++j) att[head * 625 + i * TOK + j] = ex[j] * inv;
  }
}

// ---------------- attention: att @ V -> o[25][4096]
__global__ __launch_bounds__(256) void k_attn_pv(const float* __restrict__ qkv,
                                                 const float* __restrict__ att,
                                                 float* __restrict__ o) {
  const int head = blockIdx.x;
  const int d = threadIdx.x;
  __shared__ float a[TOK * TOK];
  for (int i = threadIdx.x; i < TOK * TOK; i += 256) a[i] = att[head * 625 + i];
  __syncthreads();
  float acc[TOK];
#pragma unroll
  for (int i = 0; i < TOK; ++i) acc[i] = 0.f;
  for (int j = 0; j < TOK; ++j) {
    float vv = qkv[(long)j * 12288 + (head * 256 + d) * 3 + 2];
#pragma unroll
    for (int i = 0; i < TOK; ++i) acc[i] = fmaf(a[i * TOK + j], vv, acc[i]);
  }
#pragma unroll
  for (int i = 0; i < TOK; ++i) o[(long)i * 4096 + head * 256 + d] = acc[i];
}

extern "C" void kernel_launch(void* const* d_in, const int* in_sizes, int n_in,
                              void* d_out, int out_size, void* d_ws, size_t ws_size,
                              hipStream_t stream) {
  (void)in_sizes; (void)n_in; (void)out_size;
  const float* x      = (const float*)d_in[0];
  const float* pe_w   = (const float*)d_in[1];
  const float* pe_b   = (const float*)d_in[2];
  const float* pos    = (const float*)d_in[3];
  const float* ln_g   = (const float*)d_in[4];
  const float* ln_b   = (const float*)d_in[5];
  const float* qkv_w  = (const float*)d_in[6];
  const float* qkv_b  = (const float*)d_in[7];
  const float* proj_w = (const float*)d_in[8];
  const float* proj_b = (const float*)d_in[9];
  const float* ff1_w  = (const float*)d_in[10];
  const float* ff1_b  = (const float*)d_in[11];
  const float* ff2_w  = (const float*)d_in[12];
  const float* ff2_b  = (const float*)d_in[13];
  float* out = (float*)d_out;

  float* ws = (float*)d_ws;
  float* P    = ws;             // 102400
  float* T    = ws + 102400;    // 102400
  float* H    = ws + 204800;    // 102400
  float* QKV  = ws + 307200;    // 307200
  float* O    = ws + 614400;    // 102400
  float* G    = ws + 716800;    // 409600
  float* ATT  = ws + 1126400;   // 10000
  float* PART = ws + 1136400;
  const long avail = (long)(ws_size / 4) - 1136400;

  // pick finest KC whose partial buffer fits in workspace
  auto pick_kc = [&](int K, int Nout, int kc_min) -> int {
    for (int kc = kc_min; kc <= 512; kc <<= 1) {
      long S = K / kc;
      if (S * (long)TOK * Nout <= avail) return kc;
    }
    return 512;
  };
  auto launch_gemm = [&](const float* A, const float* W, float* part, int K,
                         int Nout, int kc) {
    dim3 g(Nout / 256, K / kc);
    switch (kc) {
      case 64:  k_gemm<64><<<g, 256, 0, stream>>>(A, W, part, K, Nout); break;
      case 128: k_gemm<128><<<g, 256, 0, stream>>>(A, W, part, K, Nout); break;
      case 256: k_gemm<256><<<g, 256, 0, stream>>>(A, W, part, K, Nout); break;
      default:  k_gemm<512><<<g, 256, 0, stream>>>(A, W, part, K, Nout); break;
    }
  };
  auto launch_gemm_wt = [&](const float* A, const float* W, float* part, int K,
                            int Nout, int kc) {
    dim3 g(Nout / 256, K / kc);
    switch (kc) {
      case 64:  k_gemm_wt<64><<<g, 256, 0, stream>>>(A, W, part, K, Nout); break;
      case 128: k_gemm_wt<128><<<g, 256, 0, stream>>>(A, W, part, K, Nout); break;
      case 256: k_gemm_wt<256><<<g, 256, 0, stream>>>(A, W, part, K, Nout); break;
      default:  k_gemm_wt<512><<<g, 256, 0, stream>>>(A, W, part, K, Nout); break;
    }
  };

  const int kc_pe   = pick_kc(4096, 4096, 64);
  const int kc_qkv  = pick_kc(4096, 12288, 128);
  const int kc_proj = pick_kc(4096, 4096, 64);
  const int kc_ff1  = pick_kc(4096, 16384, 128);
  const int kc_ff2  = pick_kc(16384, 4096, 128);

  // 1. patch embedding
  k_patchify<<<400, 256, 0, stream>>>(x, P);
  launch_gemm_wt(P, pe_w, PART, 4096, 4096, kc_pe);
  k_reduce<0, 1><<<100, 256, 0, stream>>>(PART, pe_b, pos, T, 4096, 4096 / kc_pe);

  // 2. attention branch
  k_ln<<<25, 256, 0, stream>>>(T, ln_g, ln_b, H);
  launch_gemm(H, qkv_w, PART, 4096, 12288, kc_qkv);
  k_reduce<0, 0><<<300, 256, 0, stream>>>(PART, qkv_b, nullptr, QKV, 12288, 4096 / kc_qkv);
  k_attn_qk<<<16, 256, 0, stream>>>(QKV, ATT);
  k_attn_pv<<<16, 256, 0, stream>>>(QKV, ATT, O);
  launch_gemm(O, proj_w, PART, 4096, 4096, kc_proj);
  k_reduce<0, 1><<<100, 256, 0, stream>>>(PART, proj_b, T, T, 4096, 4096 / kc_proj);

  // 3. FFN branch
  k_ln<<<25, 256, 0, stream>>>(T, ln_g, ln_b, H);
  launch_gemm(H, ff1_w, PART, 4096, 16384, kc_ff1);
  k_reduce<1, 0><<<400, 256, 0, stream>>>(PART, ff1_b, nullptr, G, 16384, 4096 / kc_ff1);
  launch_gemm(G, ff2_w, PART, 16384, 4096, kc_ff2);
  k_reduce<0, 1><<<100, 256, 0, stream>>>(PART, ff2_b, T, out, 4096, 16384 / kc_ff2);
}